// Round 5
// baseline (132.719 us; speedup 1.0000x reference)
//
#include <hip/hip_runtime.h>
#include <math.h>

// ---------------------------------------------------------------------------
// HessianLoss — per-vertex register gather with scalarized addressing.
// Grid is 2-D: blockIdx.y = row r (wave-uniform -> row base offsets live in
// SGPRs, boundary row-clamp is a scalar select, row-guards are scalar
// branches). Lanes cover 256 consecutive columns. 14 float3 loads batched,
// 6 face setups + 6 role contractions per vertex, square+weight, block
// reduce, single atomic, ticketed fused finalize. No LDS staging (R3 showed
// it is pure overhead: inputs are L2/L3-resident), no pairing (R4 showed the
// live-set spills).
// Identity: eperp(v) = cross(n, v)/|n|^2  (n = cross(v21, v02)).
// ---------------------------------------------------------------------------

struct FS { float ex, ey, ez, fx, fy, fz, area; };  // e02, e10, area

__device__ __forceinline__ FS fsetup(float3 V0, float3 V1, float3 V2)
{
    float v21x = V2.x - V1.x, v21y = V2.y - V1.y, v21z = V2.z - V1.z;
    float v02x = V0.x - V2.x, v02y = V0.y - V2.y, v02z = V0.z - V2.z;
    float v10x = V1.x - V0.x, v10y = V1.y - V0.y, v10z = V1.z - V0.z;
    float nx = v21y * v02z - v21z * v02y;
    float ny = v21z * v02x - v21x * v02z;
    float nz = v21x * v02y - v21y * v02x;
    float A2 = nx * nx + ny * ny + nz * nz;
    float inv = __builtin_amdgcn_rcpf(A2);
    FS s;
    s.ex = (ny * v02z - nz * v02y) * inv;
    s.ey = (nz * v02x - nx * v02z) * inv;
    s.ez = (nx * v02y - ny * v02x) * inv;
    s.fx = (ny * v10z - nz * v10y) * inv;
    s.fy = (nz * v10x - nx * v10z) * inv;
    s.fz = (nx * v10y - ny * v10x) * inv;
    s.area = 0.5f * sqrtf(A2);
    return s;
}

// ROLE: 0 -> i0 (k=-(e02+e10)), 1 -> i1 (k=e02), 2 -> i2 (k=e10)
template <int ROLE>
__device__ __forceinline__ void fcontrib(const FS f, float3 D0, float3 D1, float3 D2,
                                         float acc[6][3])
{
    float d1[3] = {D1.x - D0.x, D1.y - D0.y, D1.z - D0.z};
    float d2[3] = {D2.x - D0.x, D2.y - D0.y, D2.z - D0.z};
    float e[3] = {f.ex, f.ey, f.ez};
    float h[3] = {f.fx, f.fy, f.fz};
    float g[3][3];
#pragma unroll
    for (int b = 0; b < 3; ++b)
#pragma unroll
        for (int c = 0; c < 3; ++c) g[b][c] = e[b] * d1[c] + h[b] * d2[c];
    float ka[3];
#pragma unroll
    for (int a = 0; a < 3; ++a) {
        float k = (ROLE == 1) ? e[a] : (ROLE == 2) ? h[a] : -(e[a] + h[a]);
        ka[a] = f.area * k;
    }
    const int pa[6] = {0, 1, 2, 0, 0, 1};
    const int pb[6] = {0, 1, 2, 1, 2, 2};
#pragma unroll
    for (int p = 0; p < 6; ++p)
#pragma unroll
        for (int c = 0; c < 3; ++c) acc[p][c] += ka[pa[p]] * g[pb[p]][c];
}

__device__ __forceinline__ float sq_acc(const float acc[6][3])
{
    float s1 = 0.0f, s2 = 0.0f;
#pragma unroll
    for (int p = 0; p < 3; ++p)
#pragma unroll
        for (int c = 0; c < 3; ++c) s1 += acc[p][c] * acc[p][c];
#pragma unroll
    for (int p = 3; p < 6; ++p)
#pragma unroll
        for (int c = 0; c < 3; ++c) s2 += acc[p][c] * acc[p][c];
    return s1 + 2.0f * s2;
}

__device__ __forceinline__ float3 d3(float3 t, float3 v)
{
    return make_float3(t.x - v.x, t.y - v.y, t.z - v.z);
}

__global__ __launch_bounds__(256, 2)
void hess_row(const float* __restrict__ vsf, const float* __restrict__ vtf,
              float* __restrict__ acc_out, unsigned int* __restrict__ counter,
              float* __restrict__ out, int W, int H, int nblocks)
{
    const float3* vs = (const float3*)vsf;
    const float3* vt = (const float3*)vtf;
    const int c = blockIdx.x * blockDim.x + threadIdx.x;
    const int r = blockIdx.y;                 // wave-uniform

    float s = 0.0f;
    if (c < W) {
        const bool rp = (r < H - 1), rm = (r > 0);     // scalar conditions
        const bool cp = (c < W - 1), cm = (c > 0);     // per-lane (edge lanes only)

        // scalar row bases (element index), clamped
        const int rowm = (rm ? r - 1 : r) * W;
        const int row0 = r * W;
        const int rowp = (rp ? r + 1 : r) * W;
        // per-lane clamped columns
        const int ccm = cm ? c - 1 : c;
        const int ccp = cp ? c + 1 : c;

        // 7-point stencil, batched loads: vs first, then vt
        float3 Vdd = vs[rowm + ccm];   // (r-1,c-1)
        float3 Vu  = vs[rowm + c];     // (r-1,c)
        float3 Vm  = vs[row0 + ccm];   // (r,c-1)
        float3 V00 = vs[row0 + c];     // (r,c)
        float3 V01 = vs[row0 + ccp];   // (r,c+1)
        float3 V10 = vs[rowp + c];     // (r+1,c)
        float3 V11 = vs[rowp + ccp];   // (r+1,c+1)
        float3 Ddd = d3(vt[rowm + ccm], Vdd);
        float3 Du  = d3(vt[rowm + c],  Vu);
        float3 Dm  = d3(vt[row0 + ccm], Vm);
        float3 D00 = d3(vt[row0 + c],  V00);
        float3 D01 = d3(vt[row0 + ccp], V01);
        float3 D10 = d3(vt[rowp + c],  V10);
        float3 D11 = d3(vt[rowp + ccp], V11);

        float acc[6][3] = {};
        if (rp && cp) {
            fcontrib<0>(fsetup(V00, V01, V11), D00, D01, D11, acc);  // f1@(r,c) i0
            fcontrib<0>(fsetup(V00, V11, V10), D00, D11, D10, acc);  // f2@(r,c) i0
        }
        if (rp && cm)
            fcontrib<1>(fsetup(Vm, V00, V10), Dm, D00, D10, acc);    // f1@(r,c-1) i1
        if (rm && cm) {
            fcontrib<2>(fsetup(Vdd, Vu, V00), Ddd, Du, D00, acc);    // f1@(r-1,c-1) i2
            fcontrib<1>(fsetup(Vdd, V00, Vm), Ddd, D00, Dm, acc);    // f2@(r-1,c-1) i1
        }
        if (rm && cp)
            fcontrib<2>(fsetup(Vu, V01, V00), Du, D01, D00, acc);    // f2@(r-1,c) i2
        s = sq_acc(acc);
    }

    // ----- reduce + ticketed fused finalize -----
#pragma unroll
    for (int o = 32; o > 0; o >>= 1) s += __shfl_down(s, o, 64);
    __shared__ float sm[4];
    int lane = threadIdx.x & 63, wid = threadIdx.x >> 6;
    if (lane == 0) sm[wid] = s;
    __syncthreads();
    if (threadIdx.x == 0) {
        float t = sm[0] + sm[1] + sm[2] + sm[3];
        atomicAdd(acc_out, t);
        __threadfence();
        unsigned int old = atomicAdd(counter, 1u);
        if (old == (unsigned int)(nblocks - 1)) {
            float total = atomicAdd(acc_out, 0.0f);  // coherent read-back
            out[0] = total / (3.0f * (float)W * (float)H);
        }
    }
}

// ------------- fallback: 1-D per-vertex gather (any grid dims) -------------

__device__ __forceinline__ void loadP(const float3* __restrict__ vs,
                                      const float3* __restrict__ vt,
                                      int idx, float3& V, float3& D)
{
    V = vs[idx];
    D = d3(vt[idx], V);
}

__global__ void hess_gather(const float* __restrict__ vsf, const float* __restrict__ vtf,
                            float* __restrict__ acc_out, int W, int H)
{
    const float3* vs = (const float3*)vsf;
    const float3* vt = (const float3*)vtf;
    int v = blockIdx.x * blockDim.x + threadIdx.x;
    int n = W * H;
    float s = 0.0f;
    if (v < n) {
        int r = v / W;
        int c = v - r * W;
        bool rp = (r < H - 1), rm = (r >= 1), cp = (c < W - 1), cm = (c >= 1);
        float3 P00V, P00D, P01V, P01D, P11V, P11D, P10V, P10D;
        float3 PmV, PmD, PddV, PddD, PuV, PuD;
        loadP(vs, vt, v, P00V, P00D);
        loadP(vs, vt, cp ? v + 1 : v, P01V, P01D);
        loadP(vs, vt, (rp && cp) ? v + W + 1 : v, P11V, P11D);
        loadP(vs, vt, rp ? v + W : v, P10V, P10D);
        loadP(vs, vt, cm ? v - 1 : v, PmV, PmD);
        loadP(vs, vt, (rm && cm) ? v - W - 1 : v, PddV, PddD);
        loadP(vs, vt, rm ? v - W : v, PuV, PuD);
        float acc[6][3] = {};
        if (rp && cp) {
            fcontrib<0>(fsetup(P00V, P01V, P11V), P00D, P01D, P11D, acc);
            fcontrib<0>(fsetup(P00V, P11V, P10V), P00D, P11D, P10D, acc);
        }
        if (rp && cm)
            fcontrib<1>(fsetup(PmV, P00V, P10V), PmD, P00D, P10D, acc);
        if (rm && cm) {
            fcontrib<2>(fsetup(PddV, PuV, P00V), PddD, PuD, P00D, acc);
            fcontrib<1>(fsetup(PddV, P00V, PmV), PddD, P00D, PmD, acc);
        }
        if (rm && cp)
            fcontrib<2>(fsetup(PuV, P01V, P00V), PuD, P01D, P00D, acc);
        s = sq_acc(acc);
    }
#pragma unroll
    for (int o = 32; o > 0; o >>= 1) s += __shfl_down(s, o, 64);
    __shared__ float sm[4];
    int lane = threadIdx.x & 63, wid = threadIdx.x >> 6;
    if (lane == 0) sm[wid] = s;
    __syncthreads();
    if (threadIdx.x == 0) {
        float t = sm[0] + sm[1] + sm[2] + sm[3];
        atomicAdd(acc_out, t);
    }
}

__global__ void finalize(const float* __restrict__ acc, float* __restrict__ out, int n)
{
    out[0] = acc[0] / (3.0f * (float)n);
}

// ---------------------------------------------------------------------------

extern "C" void kernel_launch(void* const* d_in, const int* in_sizes, int n_in,
                              void* d_out, int out_size, void* d_ws, size_t ws_size,
                              hipStream_t stream)
{
    const float* vs = (const float*)d_in[0];
    const float* vt = (const float*)d_in[1];
    int n = in_sizes[0] / 3;
    int F = in_sizes[2] / 3;

    int W = (int)(sqrt((double)n) + 0.5);
    int H = (W > 0) ? n / W : 0;
    bool grid_ok = (W > 1) && ((long long)W * H == n) &&
                   (2LL * (W - 1) * (H - 1) == F);

    float* acc = (float*)d_ws;
    unsigned int* counter = (unsigned int*)d_ws + 1;
    hipMemsetAsync(d_ws, 0, 8, stream);

    if (grid_ok) {
        dim3 block(256, 1, 1);
        dim3 grid((W + 255) / 256, H, 1);
        int nblocks = grid.x * grid.y;
        hess_row<<<grid, block, 0, stream>>>(vs, vt, acc, counter, (float*)d_out,
                                             W, H, nblocks);
    } else {
        int threads = 256;
        int blocks = (n + threads - 1) / threads;
        hess_gather<<<blocks, threads, 0, stream>>>(vs, vt, acc, W, H);
        finalize<<<1, 1, 0, stream>>>(acc, (float*)d_out, n);
    }
}

// Round 6
// 67.766 us; speedup vs baseline: 1.9585x; 1.9585x over previous
//
#include <hip/hip_runtime.h>
#include <math.h>

// ---------------------------------------------------------------------------
// HessianLoss — per-vertex register gather, scalarized row addressing.
// blockIdx.y = row r (row bases + row clamps in SGPRs); lanes = 256 columns.
// 14 float3 loads, 6 face setups + 6 role contractions per vertex, square+
// weight, block reduce, one atomic per block. NO __threadfence / ticket:
// agent-scope fences compile to L2 writeback+invalidate per block, which
// destroyed L2 residency in R3/R4/R5 (115-155us vs R2's 60us). Finalize is a
// separate tiny kernel (~4us) instead.
// Identity: eperp(v) = cross(n, v)/|n|^2  (n = cross(v21, v02)).
// ---------------------------------------------------------------------------

struct FS { float ex, ey, ez, fx, fy, fz, area; };  // e02, e10, area

__device__ __forceinline__ FS fsetup(float3 V0, float3 V1, float3 V2)
{
    float v21x = V2.x - V1.x, v21y = V2.y - V1.y, v21z = V2.z - V1.z;
    float v02x = V0.x - V2.x, v02y = V0.y - V2.y, v02z = V0.z - V2.z;
    float v10x = V1.x - V0.x, v10y = V1.y - V0.y, v10z = V1.z - V0.z;
    float nx = v21y * v02z - v21z * v02y;
    float ny = v21z * v02x - v21x * v02z;
    float nz = v21x * v02y - v21y * v02x;
    float A2 = nx * nx + ny * ny + nz * nz;
    float inv = __builtin_amdgcn_rcpf(A2);
    FS s;
    s.ex = (ny * v02z - nz * v02y) * inv;
    s.ey = (nz * v02x - nx * v02z) * inv;
    s.ez = (nx * v02y - ny * v02x) * inv;
    s.fx = (ny * v10z - nz * v10y) * inv;
    s.fy = (nz * v10x - nx * v10z) * inv;
    s.fz = (nx * v10y - ny * v10x) * inv;
    s.area = 0.5f * sqrtf(A2);
    return s;
}

// ROLE: 0 -> i0 (k=-(e02+e10)), 1 -> i1 (k=e02), 2 -> i2 (k=e10)
template <int ROLE>
__device__ __forceinline__ void fcontrib(const FS f, float3 D0, float3 D1, float3 D2,
                                         float acc[6][3])
{
    float d1[3] = {D1.x - D0.x, D1.y - D0.y, D1.z - D0.z};
    float d2[3] = {D2.x - D0.x, D2.y - D0.y, D2.z - D0.z};
    float e[3] = {f.ex, f.ey, f.ez};
    float h[3] = {f.fx, f.fy, f.fz};
    float g[3][3];
#pragma unroll
    for (int b = 0; b < 3; ++b)
#pragma unroll
        for (int c = 0; c < 3; ++c) g[b][c] = e[b] * d1[c] + h[b] * d2[c];
    float ka[3];
#pragma unroll
    for (int a = 0; a < 3; ++a) {
        float k = (ROLE == 1) ? e[a] : (ROLE == 2) ? h[a] : -(e[a] + h[a]);
        ka[a] = f.area * k;
    }
    const int pa[6] = {0, 1, 2, 0, 0, 1};
    const int pb[6] = {0, 1, 2, 1, 2, 2};
#pragma unroll
    for (int p = 0; p < 6; ++p)
#pragma unroll
        for (int c = 0; c < 3; ++c) acc[p][c] += ka[pa[p]] * g[pb[p]][c];
}

__device__ __forceinline__ float sq_acc(const float acc[6][3])
{
    float s1 = 0.0f, s2 = 0.0f;
#pragma unroll
    for (int p = 0; p < 3; ++p)
#pragma unroll
        for (int c = 0; c < 3; ++c) s1 += acc[p][c] * acc[p][c];
#pragma unroll
    for (int p = 3; p < 6; ++p)
#pragma unroll
        for (int c = 0; c < 3; ++c) s2 += acc[p][c] * acc[p][c];
    return s1 + 2.0f * s2;
}

__device__ __forceinline__ float3 d3(float3 t, float3 v)
{
    return make_float3(t.x - v.x, t.y - v.y, t.z - v.z);
}

__global__ __launch_bounds__(256)
void hess_row(const float* __restrict__ vsf, const float* __restrict__ vtf,
              float* __restrict__ acc_out, int W, int H)
{
    const float3* vs = (const float3*)vsf;
    const float3* vt = (const float3*)vtf;
    const int c = blockIdx.x * blockDim.x + threadIdx.x;
    const int r = blockIdx.y;                 // wave-uniform

    float s = 0.0f;
    if (c < W) {
        const bool rp = (r < H - 1), rm = (r > 0);     // scalar conditions
        const bool cp = (c < W - 1), cm = (c > 0);     // per-lane (edge lanes only)

        const int rowm = (rm ? r - 1 : r) * W;
        const int row0 = r * W;
        const int rowp = (rp ? r + 1 : r) * W;
        const int ccm = cm ? c - 1 : c;
        const int ccp = cp ? c + 1 : c;

        // 7-point stencil, loads batched: all vs, then all vt
        float3 Vdd = vs[rowm + ccm];   // (r-1,c-1)
        float3 Vu  = vs[rowm + c];     // (r-1,c)
        float3 Vm  = vs[row0 + ccm];   // (r,c-1)
        float3 V00 = vs[row0 + c];     // (r,c)
        float3 V01 = vs[row0 + ccp];   // (r,c+1)
        float3 V10 = vs[rowp + c];     // (r+1,c)
        float3 V11 = vs[rowp + ccp];   // (r+1,c+1)
        float3 Tdd = vt[rowm + ccm];
        float3 Tu  = vt[rowm + c];
        float3 Tm  = vt[row0 + ccm];
        float3 T00 = vt[row0 + c];
        float3 T01 = vt[row0 + ccp];
        float3 T10 = vt[rowp + c];
        float3 T11 = vt[rowp + ccp];
        float3 Ddd = d3(Tdd, Vdd), Du = d3(Tu, Vu);
        float3 Dm = d3(Tm, Vm), D00 = d3(T00, V00), D01 = d3(T01, V01);
        float3 D10 = d3(T10, V10), D11 = d3(T11, V11);

        float acc[6][3] = {};
        if (rp && cp) {
            fcontrib<0>(fsetup(V00, V01, V11), D00, D01, D11, acc);  // f1@(r,c) i0
            fcontrib<0>(fsetup(V00, V11, V10), D00, D11, D10, acc);  // f2@(r,c) i0
        }
        if (rp && cm)
            fcontrib<1>(fsetup(Vm, V00, V10), Dm, D00, D10, acc);    // f1@(r,c-1) i1
        if (rm && cm) {
            fcontrib<2>(fsetup(Vdd, Vu, V00), Ddd, Du, D00, acc);    // f1@(r-1,c-1) i2
            fcontrib<1>(fsetup(Vdd, V00, Vm), Ddd, D00, Dm, acc);    // f2@(r-1,c-1) i1
        }
        if (rm && cp)
            fcontrib<2>(fsetup(Vu, V01, V00), Du, D01, D00, acc);    // f2@(r-1,c) i2
        s = sq_acc(acc);
    }

    // ----- block reduce + one atomic -----
#pragma unroll
    for (int o = 32; o > 0; o >>= 1) s += __shfl_down(s, o, 64);
    __shared__ float sm[4];
    int lane = threadIdx.x & 63, wid = threadIdx.x >> 6;
    if (lane == 0) sm[wid] = s;
    __syncthreads();
    if (threadIdx.x == 0) {
        float t = sm[0] + sm[1] + sm[2] + sm[3];
        atomicAdd(acc_out, t);
    }
}

// ------------- fallback: 1-D per-vertex gather (any grid dims) -------------

__device__ __forceinline__ void loadP(const float3* __restrict__ vs,
                                      const float3* __restrict__ vt,
                                      int idx, float3& V, float3& D)
{
    V = vs[idx];
    D = d3(vt[idx], V);
}

__global__ void hess_gather(const float* __restrict__ vsf, const float* __restrict__ vtf,
                            float* __restrict__ acc_out, int W, int H)
{
    const float3* vs = (const float3*)vsf;
    const float3* vt = (const float3*)vtf;
    int v = blockIdx.x * blockDim.x + threadIdx.x;
    int n = W * H;
    float s = 0.0f;
    if (v < n) {
        int r = v / W;
        int c = v - r * W;
        bool rp = (r < H - 1), rm = (r >= 1), cp = (c < W - 1), cm = (c >= 1);
        float3 P00V, P00D, P01V, P01D, P11V, P11D, P10V, P10D;
        float3 PmV, PmD, PddV, PddD, PuV, PuD;
        loadP(vs, vt, v, P00V, P00D);
        loadP(vs, vt, cp ? v + 1 : v, P01V, P01D);
        loadP(vs, vt, (rp && cp) ? v + W + 1 : v, P11V, P11D);
        loadP(vs, vt, rp ? v + W : v, P10V, P10D);
        loadP(vs, vt, cm ? v - 1 : v, PmV, PmD);
        loadP(vs, vt, (rm && cm) ? v - W - 1 : v, PddV, PddD);
        loadP(vs, vt, rm ? v - W : v, PuV, PuD);
        float acc[6][3] = {};
        if (rp && cp) {
            fcontrib<0>(fsetup(P00V, P01V, P11V), P00D, P01D, P11D, acc);
            fcontrib<0>(fsetup(P00V, P11V, P10V), P00D, P11D, P10D, acc);
        }
        if (rp && cm)
            fcontrib<1>(fsetup(PmV, P00V, P10V), PmD, P00D, P10D, acc);
        if (rm && cm) {
            fcontrib<2>(fsetup(PddV, PuV, P00V), PddD, PuD, P00D, acc);
            fcontrib<1>(fsetup(PddV, P00V, PmV), PddD, P00D, PmD, acc);
        }
        if (rm && cp)
            fcontrib<2>(fsetup(PuV, P01V, P00V), PuD, P01D, P00D, acc);
        s = sq_acc(acc);
    }
#pragma unroll
    for (int o = 32; o > 0; o >>= 1) s += __shfl_down(s, o, 64);
    __shared__ float sm[4];
    int lane = threadIdx.x & 63, wid = threadIdx.x >> 6;
    if (lane == 0) sm[wid] = s;
    __syncthreads();
    if (threadIdx.x == 0) {
        float t = sm[0] + sm[1] + sm[2] + sm[3];
        atomicAdd(acc_out, t);
    }
}

__global__ void finalize(const float* __restrict__ acc, float* __restrict__ out, int n)
{
    out[0] = acc[0] / (3.0f * (float)n);
}

// ---------------------------------------------------------------------------

extern "C" void kernel_launch(void* const* d_in, const int* in_sizes, int n_in,
                              void* d_out, int out_size, void* d_ws, size_t ws_size,
                              hipStream_t stream)
{
    const float* vs = (const float*)d_in[0];
    const float* vt = (const float*)d_in[1];
    int n = in_sizes[0] / 3;
    int F = in_sizes[2] / 3;

    int W = (int)(sqrt((double)n) + 0.5);
    int H = (W > 0) ? n / W : 0;
    bool grid_ok = (W > 1) && ((long long)W * H == n) &&
                   (2LL * (W - 1) * (H - 1) == F);

    float* acc = (float*)d_ws;
    hipMemsetAsync(acc, 0, sizeof(float), stream);

    if (grid_ok) {
        dim3 block(256, 1, 1);
        dim3 grid((W + 255) / 256, H, 1);
        hess_row<<<grid, block, 0, stream>>>(vs, vt, acc, W, H);
    } else {
        int threads = 256;
        int blocks = (n + threads - 1) / threads;
        hess_gather<<<blocks, threads, 0, stream>>>(vs, vt, acc, W, H);
    }
    finalize<<<1, 1, 0, stream>>>(acc, (float*)d_out, n);
}

// Round 7
// 34.612 us; speedup vs baseline: 3.8344x; 1.9578x over previous
//
#include <hip/hip_runtime.h>
#include <math.h>

// ---------------------------------------------------------------------------
// HessianLoss — vertical register-march gather (K rows per thread).
// Thread owns column c, marches rows r0..r0+K-1. Steady state per vertex:
//   - rotate stencil points in registers; load only 3 new points (6 loads
//     vs 14 for the one-shot kernel)
//   - carry 2 of 6 face setups (F4' = F3, F6' = F2), compute 4 fresh
// Face/role table (identical math to the verified R6 kernel):
//   F1=f1@(r,c) i0      F2=f2@(r,c) i0      F3=f1@(r,c-1) i1
//   F4=f1@(r-1,c-1) i2  F5=f2@(r-1,c-1) i1  F6=f2@(r-1,c) i2
// NO __threadfence (R3-R5: agent-scope fence = L2 invalidate per block,
// +80us). No LDS staging (R3: pure overhead, inputs are L2/L3-resident).
// Plain __launch_bounds__(256) (R4: starved allocator -> scratch spill).
// Identity: eperp(v) = cross(n, v)/|n|^2  (n = cross(v21, v02)).
// ---------------------------------------------------------------------------

struct FS { float ex, ey, ez, fx, fy, fz, area; };  // e02, e10, area

__device__ __forceinline__ FS fsetup(float3 V0, float3 V1, float3 V2)
{
    float v21x = V2.x - V1.x, v21y = V2.y - V1.y, v21z = V2.z - V1.z;
    float v02x = V0.x - V2.x, v02y = V0.y - V2.y, v02z = V0.z - V2.z;
    float v10x = V1.x - V0.x, v10y = V1.y - V0.y, v10z = V1.z - V0.z;
    float nx = v21y * v02z - v21z * v02y;
    float ny = v21z * v02x - v21x * v02z;
    float nz = v21x * v02y - v21y * v02x;
    float A2 = nx * nx + ny * ny + nz * nz;
    float inv = __builtin_amdgcn_rcpf(A2);
    FS s;
    s.ex = (ny * v02z - nz * v02y) * inv;
    s.ey = (nz * v02x - nx * v02z) * inv;
    s.ez = (nx * v02y - ny * v02x) * inv;
    s.fx = (ny * v10z - nz * v10y) * inv;
    s.fy = (nz * v10x - nx * v10z) * inv;
    s.fz = (nx * v10y - ny * v10x) * inv;
    s.area = 0.5f * sqrtf(A2);
    return s;
}

// ROLE: 0 -> i0 (k=-(e02+e10)), 1 -> i1 (k=e02), 2 -> i2 (k=e10)
template <int ROLE>
__device__ __forceinline__ void fcontrib(const FS f, float3 D0, float3 D1, float3 D2,
                                         float acc[6][3])
{
    float d1[3] = {D1.x - D0.x, D1.y - D0.y, D1.z - D0.z};
    float d2[3] = {D2.x - D0.x, D2.y - D0.y, D2.z - D0.z};
    float e[3] = {f.ex, f.ey, f.ez};
    float h[3] = {f.fx, f.fy, f.fz};
    float g[3][3];
#pragma unroll
    for (int b = 0; b < 3; ++b)
#pragma unroll
        for (int c = 0; c < 3; ++c) g[b][c] = e[b] * d1[c] + h[b] * d2[c];
    float ka[3];
#pragma unroll
    for (int a = 0; a < 3; ++a) {
        float k = (ROLE == 1) ? e[a] : (ROLE == 2) ? h[a] : -(e[a] + h[a]);
        ka[a] = f.area * k;
    }
    const int pa[6] = {0, 1, 2, 0, 0, 1};
    const int pb[6] = {0, 1, 2, 1, 2, 2};
#pragma unroll
    for (int p = 0; p < 6; ++p)
#pragma unroll
        for (int c = 0; c < 3; ++c) acc[p][c] += ka[pa[p]] * g[pb[p]][c];
}

__device__ __forceinline__ float sq_acc(const float acc[6][3])
{
    float s1 = 0.0f, s2 = 0.0f;
#pragma unroll
    for (int p = 0; p < 3; ++p)
#pragma unroll
        for (int c = 0; c < 3; ++c) s1 += acc[p][c] * acc[p][c];
#pragma unroll
    for (int p = 3; p < 6; ++p)
#pragma unroll
        for (int c = 0; c < 3; ++c) s2 += acc[p][c] * acc[p][c];
    return s1 + 2.0f * s2;
}

__device__ __forceinline__ float3 d3(float3 t, float3 v)
{
    return make_float3(t.x - v.x, t.y - v.y, t.z - v.z);
}

#define MK 4  // rows marched per thread

__global__ __launch_bounds__(256)
void hess_march(const float* __restrict__ vsf, const float* __restrict__ vtf,
                float* __restrict__ acc_out, int W, int H)
{
    const float3* vs = (const float3*)vsf;
    const float3* vt = (const float3*)vtf;
    const int c = blockIdx.x * blockDim.x + threadIdx.x;
    const int r0 = blockIdx.y * MK;            // wave-uniform

    float s = 0.0f;
    if (c < W) {
        const bool cp = (c < W - 1), cm = (c > 0);
        const int ccm = cm ? c - 1 : c;
        const int ccp = cp ? c + 1 : c;

        // ---- prologue: 7-point stencil for vertex (r0, c) ----
        const int rowm = (r0 > 0 ? r0 - 1 : 0) * W;
        const int row0 = r0 * W;
        const int rowp = (r0 < H - 1 ? r0 + 1 : H - 1) * W;

        float3 Vdd = vs[rowm + ccm], Vu = vs[rowm + c];
        float3 Vm  = vs[row0 + ccm], V00 = vs[row0 + c], V01 = vs[row0 + ccp];
        float3 V10 = vs[rowp + c],   V11 = vs[rowp + ccp];
        float3 Ddd = d3(vt[rowm + ccm], Vdd), Du = d3(vt[rowm + c], Vu);
        float3 Dm  = d3(vt[row0 + ccm], Vm);
        float3 D00 = d3(vt[row0 + c], V00), D01 = d3(vt[row0 + ccp], V01);
        float3 D10 = d3(vt[rowp + c], V10), D11 = d3(vt[rowp + ccp], V11);

        FS F4 = fsetup(Vdd, Vu, V00);   // f1@(r0-1,c-1)  (garbage if r0==0; guarded)
        FS F6 = fsetup(Vu, V01, V00);   // f2@(r0-1,c)

#pragma unroll
        for (int k = 0; k < MK; ++k) {
            const int r = r0 + k;
            const bool rp = (r < H - 1), rm = (r > 0);   // scalar

            FS F1 = fsetup(V00, V01, V11);   // f1@(r,c)
            FS F2 = fsetup(V00, V11, V10);   // f2@(r,c)
            FS F3 = fsetup(Vm, V00, V10);    // f1@(r,c-1)
            FS F5 = fsetup(Vdd, V00, Vm);    // f2@(r-1,c-1)

            float acc[6][3] = {};
            if (rp && cp) {
                fcontrib<0>(F1, D00, D01, D11, acc);
                fcontrib<0>(F2, D00, D11, D10, acc);
            }
            if (rp && cm)
                fcontrib<1>(F3, Dm, D00, D10, acc);
            if (rm && cm) {
                fcontrib<2>(F4, Ddd, Du, D00, acc);
                fcontrib<1>(F5, Ddd, D00, Dm, acc);
            }
            if (rm && cp)
                fcontrib<2>(F6, Du, D01, D00, acc);
            s += sq_acc(acc);

            if (k < MK - 1) {
                // rows: r+1 is always valid here (strip interior); clamp r+2
                const int rowa = (r + 1) * W;
                const int rowb = (r + 2 < H ? r + 2 : H - 1) * W;
                float3 nVm  = vs[rowa + ccm];
                float3 nV10 = vs[rowb + c];
                float3 nV11 = vs[rowb + ccp];
                float3 nTm  = vt[rowa + ccm];
                float3 nT10 = vt[rowb + c];
                float3 nT11 = vt[rowb + ccp];
                // rotate (order matters: read-before-overwrite)
                Vdd = Vm;  Ddd = Dm;
                Du  = D00;
                Vm  = nVm;  Dm  = d3(nTm, nVm);
                V00 = V10;  D00 = D10;
                V01 = V11;  D01 = D11;
                V10 = nV10; D10 = d3(nT10, nV10);
                V11 = nV11; D11 = d3(nT11, nV11);
                F4 = F3;  F6 = F2;
            }
        }
    }

    // ----- block reduce + one atomic -----
#pragma unroll
    for (int o = 32; o > 0; o >>= 1) s += __shfl_down(s, o, 64);
    __shared__ float sm[4];
    int lane = threadIdx.x & 63, wid = threadIdx.x >> 6;
    if (lane == 0) sm[wid] = s;
    __syncthreads();
    if (threadIdx.x == 0) {
        float t = sm[0] + sm[1] + sm[2] + sm[3];
        atomicAdd(acc_out, t);
    }
}

// ------------- fallback: 1-D per-vertex gather (any grid dims) -------------

__device__ __forceinline__ void loadP(const float3* __restrict__ vs,
                                      const float3* __restrict__ vt,
                                      int idx, float3& V, float3& D)
{
    V = vs[idx];
    D = d3(vt[idx], V);
}

__global__ void hess_gather(const float* __restrict__ vsf, const float* __restrict__ vtf,
                            float* __restrict__ acc_out, int W, int H)
{
    const float3* vs = (const float3*)vsf;
    const float3* vt = (const float3*)vtf;
    int v = blockIdx.x * blockDim.x + threadIdx.x;
    int n = W * H;
    float s = 0.0f;
    if (v < n) {
        int r = v / W;
        int c = v - r * W;
        bool rp = (r < H - 1), rm = (r >= 1), cp = (c < W - 1), cm = (c >= 1);
        float3 P00V, P00D, P01V, P01D, P11V, P11D, P10V, P10D;
        float3 PmV, PmD, PddV, PddD, PuV, PuD;
        loadP(vs, vt, v, P00V, P00D);
        loadP(vs, vt, cp ? v + 1 : v, P01V, P01D);
        loadP(vs, vt, (rp && cp) ? v + W + 1 : v, P11V, P11D);
        loadP(vs, vt, rp ? v + W : v, P10V, P10D);
        loadP(vs, vt, cm ? v - 1 : v, PmV, PmD);
        loadP(vs, vt, (rm && cm) ? v - W - 1 : v, PddV, PddD);
        loadP(vs, vt, rm ? v - W : v, PuV, PuD);
        float acc[6][3] = {};
        if (rp && cp) {
            fcontrib<0>(fsetup(P00V, P01V, P11V), P00D, P01D, P11D, acc);
            fcontrib<0>(fsetup(P00V, P11V, P10V), P00D, P11D, P10D, acc);
        }
        if (rp && cm)
            fcontrib<1>(fsetup(PmV, P00V, P10V), PmD, P00D, P10D, acc);
        if (rm && cm) {
            fcontrib<2>(fsetup(PddV, PuV, P00V), PddD, PuD, P00D, acc);
            fcontrib<1>(fsetup(PddV, P00V, PmV), PddD, P00D, PmD, acc);
        }
        if (rm && cp)
            fcontrib<2>(fsetup(PuV, P01V, P00V), PuD, P01D, P00D, acc);
        s = sq_acc(acc);
    }
#pragma unroll
    for (int o = 32; o > 0; o >>= 1) s += __shfl_down(s, o, 64);
    __shared__ float sm[4];
    int lane = threadIdx.x & 63, wid = threadIdx.x >> 6;
    if (lane == 0) sm[wid] = s;
    __syncthreads();
    if (threadIdx.x == 0) {
        float t = sm[0] + sm[1] + sm[2] + sm[3];
        atomicAdd(acc_out, t);
    }
}

__global__ void finalize(const float* __restrict__ acc, float* __restrict__ out, int n)
{
    out[0] = acc[0] / (3.0f * (float)n);
}

// ---------------------------------------------------------------------------

extern "C" void kernel_launch(void* const* d_in, const int* in_sizes, int n_in,
                              void* d_out, int out_size, void* d_ws, size_t ws_size,
                              hipStream_t stream)
{
    const float* vs = (const float*)d_in[0];
    const float* vt = (const float*)d_in[1];
    int n = in_sizes[0] / 3;
    int F = in_sizes[2] / 3;

    int W = (int)(sqrt((double)n) + 0.5);
    int H = (W > 0) ? n / W : 0;
    bool grid_ok = (W > 1) && ((long long)W * H == n) &&
                   (2LL * (W - 1) * (H - 1) == F);

    float* acc = (float*)d_ws;
    hipMemsetAsync(acc, 0, sizeof(float), stream);

    if (grid_ok && (H % MK == 0)) {
        dim3 block(256, 1, 1);
        dim3 grid((W + 255) / 256, H / MK, 1);
        hess_march<<<grid, block, 0, stream>>>(vs, vt, acc, W, H);
    } else {
        int threads = 256;
        int blocks = (n + threads - 1) / threads;
        hess_gather<<<blocks, threads, 0, stream>>>(vs, vt, acc, W, H);
    }
    finalize<<<1, 1, 0, stream>>>(acc, (float*)d_out, n);
}

// Round 8
// 30.849 us; speedup vs baseline: 4.3022x; 1.1220x over previous
//
#include <hip/hip_runtime.h>
#include <math.h>

// ---------------------------------------------------------------------------
// HessianLoss — vertical register-march + wave-shuffle load sharing.
// Thread owns column c, marches MK rows. Steady state per vertex:
//   - 2 own-column loads (vs/vt at (r+2,c)); neighbor-column points come from
//     adjacent lanes via __shfl (wave-edge lanes patch with masked loads)
//   - 4 fresh face setups, 2 carried (F4'=F3, F6'=F2)
// Face/role table (identical math to verified R6/R7):
//   F1=f1@(r,c) i0      F2=f2@(r,c) i0      F3=f1@(r,c-1) i1
//   F4=f1@(r-1,c-1) i2  F5=f2@(r-1,c-1) i1  F6=f2@(r-1,c) i2
// Reduction: per-block partial stores (no memset, no global atomic, no
// __threadfence — R3-R5 showed agent-scope fences invalidate L2, +80us),
// then one 256-thread reduce kernel.
// Identity: eperp(v) = cross(n, v)/|n|^2  (n = cross(v21, v02)).
// ---------------------------------------------------------------------------

struct FS { float ex, ey, ez, fx, fy, fz, area; };  // e02, e10, area

__device__ __forceinline__ FS fsetup(float3 V0, float3 V1, float3 V2)
{
    float v21x = V2.x - V1.x, v21y = V2.y - V1.y, v21z = V2.z - V1.z;
    float v02x = V0.x - V2.x, v02y = V0.y - V2.y, v02z = V0.z - V2.z;
    float v10x = V1.x - V0.x, v10y = V1.y - V0.y, v10z = V1.z - V0.z;
    float nx = v21y * v02z - v21z * v02y;
    float ny = v21z * v02x - v21x * v02z;
    float nz = v21x * v02y - v21y * v02x;
    float A2 = nx * nx + ny * ny + nz * nz;
    float inv = __builtin_amdgcn_rcpf(A2);
    FS s;
    s.ex = (ny * v02z - nz * v02y) * inv;
    s.ey = (nz * v02x - nx * v02z) * inv;
    s.ez = (nx * v02y - ny * v02x) * inv;
    s.fx = (ny * v10z - nz * v10y) * inv;
    s.fy = (nz * v10x - nx * v10z) * inv;
    s.fz = (nx * v10y - ny * v10x) * inv;
    s.area = 0.5f * sqrtf(A2);
    return s;
}

// ROLE: 0 -> i0 (k=-(e02+e10)), 1 -> i1 (k=e02), 2 -> i2 (k=e10)
template <int ROLE>
__device__ __forceinline__ void fcontrib(const FS f, float3 D0, float3 D1, float3 D2,
                                         float acc[6][3])
{
    float d1[3] = {D1.x - D0.x, D1.y - D0.y, D1.z - D0.z};
    float d2[3] = {D2.x - D0.x, D2.y - D0.y, D2.z - D0.z};
    float e[3] = {f.ex, f.ey, f.ez};
    float h[3] = {f.fx, f.fy, f.fz};
    float g[3][3];
#pragma unroll
    for (int b = 0; b < 3; ++b)
#pragma unroll
        for (int c = 0; c < 3; ++c) g[b][c] = e[b] * d1[c] + h[b] * d2[c];
    float ka[3];
#pragma unroll
    for (int a = 0; a < 3; ++a) {
        float k = (ROLE == 1) ? e[a] : (ROLE == 2) ? h[a] : -(e[a] + h[a]);
        ka[a] = f.area * k;
    }
    const int pa[6] = {0, 1, 2, 0, 0, 1};
    const int pb[6] = {0, 1, 2, 1, 2, 2};
#pragma unroll
    for (int p = 0; p < 6; ++p)
#pragma unroll
        for (int c = 0; c < 3; ++c) acc[p][c] += ka[pa[p]] * g[pb[p]][c];
}

__device__ __forceinline__ float sq_acc(const float acc[6][3])
{
    float s1 = 0.0f, s2 = 0.0f;
#pragma unroll
    for (int p = 0; p < 3; ++p)
#pragma unroll
        for (int c = 0; c < 3; ++c) s1 += acc[p][c] * acc[p][c];
#pragma unroll
    for (int p = 3; p < 6; ++p)
#pragma unroll
        for (int c = 0; c < 3; ++c) s2 += acc[p][c] * acc[p][c];
    return s1 + 2.0f * s2;
}

__device__ __forceinline__ float3 d3(float3 t, float3 v)
{
    return make_float3(t.x - v.x, t.y - v.y, t.z - v.z);
}

__device__ __forceinline__ float3 shfl_up3(float3 v)
{
    return make_float3(__shfl_up(v.x, 1, 64), __shfl_up(v.y, 1, 64),
                       __shfl_up(v.z, 1, 64));
}
__device__ __forceinline__ float3 shfl_dn3(float3 v)
{
    return make_float3(__shfl_down(v.x, 1, 64), __shfl_down(v.y, 1, 64),
                       __shfl_down(v.z, 1, 64));
}

#define MK 4  // rows marched per thread

__global__ __launch_bounds__(256)
void hess_march2(const float* __restrict__ vsf, const float* __restrict__ vtf,
                 float* __restrict__ partials, int W, int H)
{
    const float3* vs = (const float3*)vsf;
    const float3* vt = (const float3*)vtf;
    const int tid = threadIdx.x;
    const int lane = tid & 63;
    const int c = blockIdx.x * blockDim.x + tid;
    const int cL = (c < W) ? c : W - 1;        // clamp for loads; lanes c>=W zeroed
    const int r0 = blockIdx.y * MK;            // wave-uniform
    const bool cp = (c < W - 1), cm = (c > 0);
    const int ccm = cm ? cL - 1 : cL;
    const int ccp = cp ? cL + 1 : cL;

    // ---- prologue: own-column loads rows r0-1, r0, r0+1; neighbors by shfl ----
    const int rowm = (r0 > 0 ? r0 - 1 : 0) * W;
    const int row0 = r0 * W;
    const int rowp = (r0 + 1 < H ? r0 + 1 : H - 1) * W;

    float3 A = vs[rowm + cL];  float3 dA = d3(vt[rowm + cL], A);
    float3 B = vs[row0 + cL];  float3 dB = d3(vt[row0 + cL], B);
    float3 C = vs[rowp + cL];  float3 dC = d3(vt[rowp + cL], C);

    float3 Vu = A, Du = dA;
    float3 V00 = B, D00 = dB;
    float3 V10 = C, D10 = dC;

    float3 Vdd = shfl_up3(A), Ddd = shfl_up3(dA);
    float3 Vm  = shfl_up3(B), Dm  = shfl_up3(dB);
    float3 V01 = shfl_dn3(B), D01 = shfl_dn3(dB);
    float3 V11 = shfl_dn3(C), D11 = shfl_dn3(dC);
    if (lane == 0) {   // wave-left edge: true left-column values
        float3 v = vs[rowm + ccm]; Vdd = v; Ddd = d3(vt[rowm + ccm], v);
        v = vs[row0 + ccm]; Vm = v; Dm = d3(vt[row0 + ccm], v);
    }
    if (lane == 63) {  // wave-right edge
        float3 v = vs[row0 + ccp]; V01 = v; D01 = d3(vt[row0 + ccp], v);
        v = vs[rowp + ccp]; V11 = v; D11 = d3(vt[rowp + ccp], v);
    }

    FS F4 = fsetup(Vdd, Vu, V00);   // f1@(r0-1,c-1)  (garbage if r0==0; guarded)
    FS F6 = fsetup(Vu, V01, V00);   // f2@(r0-1,c)

    float s = 0.0f;
#pragma unroll
    for (int k = 0; k < MK; ++k) {
        const int r = r0 + k;
        const bool rp = (r < H - 1), rm = (r > 0);   // scalar

        // ---- prefetch next rows (issued before compute; consumed at rotate) ----
        float3 P2 = make_float3(0.f, 0.f, 0.f), T2 = P2;
        float3 PmL = P2, TmL = P2, P2p = P2, T2p = P2;
        if (k < MK - 1) {
            const int rowa = (r + 1) * W;
            const int rowb = (r + 2 < H ? r + 2 : H - 1) * W;
            P2 = vs[rowb + cL];
            T2 = vt[rowb + cL];
            if (lane == 0)  { PmL = vs[rowa + ccm]; TmL = vt[rowa + ccm]; }
            if (lane == 63) { P2p = vs[rowb + ccp]; T2p = vt[rowb + ccp]; }
        }

        // ---- compute current row ----
        FS F1 = fsetup(V00, V01, V11);   // f1@(r,c)
        FS F2 = fsetup(V00, V11, V10);   // f2@(r,c)
        FS F3 = fsetup(Vm, V00, V10);    // f1@(r,c-1)
        FS F5 = fsetup(Vdd, V00, Vm);    // f2@(r-1,c-1)

        float acc[6][3] = {};
        if (rp && cp) {
            fcontrib<0>(F1, D00, D01, D11, acc);
            fcontrib<0>(F2, D00, D11, D10, acc);
        }
        if (rp && cm)
            fcontrib<1>(F3, Dm, D00, D10, acc);
        if (rm && cm) {
            fcontrib<2>(F4, Ddd, Du, D00, acc);
            fcontrib<1>(F5, Ddd, D00, Dm, acc);
        }
        if (rm && cp)
            fcontrib<2>(F6, Du, D01, D00, acc);
        s += sq_acc(acc);

        // ---- rotate (shfl outside any divergent guard) ----
        if (k < MK - 1) {
            float3 D2 = d3(T2, P2);
            float3 nVm = shfl_up3(V10), nDm = shfl_up3(D10);
            float3 nV11 = shfl_dn3(P2), nD11 = shfl_dn3(D2);
            if (lane == 0)  { nVm = PmL; nDm = d3(TmL, PmL); }
            if (lane == 63) { nV11 = P2p; nD11 = d3(T2p, P2p); }
            Vdd = Vm;  Ddd = Dm;
            Du  = D00;
            Vm  = nVm;  Dm  = nDm;
            V00 = V10;  D00 = D10;
            V01 = V11;  D01 = D11;
            V10 = P2;   D10 = D2;
            V11 = nV11; D11 = nD11;
            F4 = F3;  F6 = F2;
        }
    }
    if (c >= W) s = 0.0f;   // overwrite (not add): kills NaN from clamped lanes

    // ---- block reduce + plain partial store (no atomic, no init needed) ----
#pragma unroll
    for (int o = 32; o > 0; o >>= 1) s += __shfl_down(s, o, 64);
    __shared__ float sm[4];
    int wid = tid >> 6;
    if (lane == 0) sm[wid] = s;
    __syncthreads();
    if (tid == 0)
        partials[blockIdx.y * gridDim.x + blockIdx.x] = sm[0] + sm[1] + sm[2] + sm[3];
}

// ------------- fallback: 1-D per-vertex gather (any grid dims) -------------

__device__ __forceinline__ void loadP(const float3* __restrict__ vs,
                                      const float3* __restrict__ vt,
                                      int idx, float3& V, float3& D)
{
    V = vs[idx];
    D = d3(vt[idx], V);
}

__global__ void hess_gather(const float* __restrict__ vsf, const float* __restrict__ vtf,
                            float* __restrict__ partials, int W, int H)
{
    const float3* vs = (const float3*)vsf;
    const float3* vt = (const float3*)vtf;
    int v = blockIdx.x * blockDim.x + threadIdx.x;
    int n = W * H;
    float s = 0.0f;
    if (v < n) {
        int r = v / W;
        int c = v - r * W;
        bool rp = (r < H - 1), rm = (r >= 1), cp = (c < W - 1), cm = (c >= 1);
        float3 P00V, P00D, P01V, P01D, P11V, P11D, P10V, P10D;
        float3 PmV, PmD, PddV, PddD, PuV, PuD;
        loadP(vs, vt, v, P00V, P00D);
        loadP(vs, vt, cp ? v + 1 : v, P01V, P01D);
        loadP(vs, vt, (rp && cp) ? v + W + 1 : v, P11V, P11D);
        loadP(vs, vt, rp ? v + W : v, P10V, P10D);
        loadP(vs, vt, cm ? v - 1 : v, PmV, PmD);
        loadP(vs, vt, (rm && cm) ? v - W - 1 : v, PddV, PddD);
        loadP(vs, vt, rm ? v - W : v, PuV, PuD);
        float acc[6][3] = {};
        if (rp && cp) {
            fcontrib<0>(fsetup(P00V, P01V, P11V), P00D, P01D, P11D, acc);
            fcontrib<0>(fsetup(P00V, P11V, P10V), P00D, P11D, P10D, acc);
        }
        if (rp && cm)
            fcontrib<1>(fsetup(PmV, P00V, P10V), PmD, P00D, P10D, acc);
        if (rm && cm) {
            fcontrib<2>(fsetup(PddV, PuV, P00V), PddD, PuD, P00D, acc);
            fcontrib<1>(fsetup(PddV, P00V, PmV), PddD, P00D, PmD, acc);
        }
        if (rm && cp)
            fcontrib<2>(fsetup(PuV, P01V, P00V), PuD, P01D, P00D, acc);
        s = sq_acc(acc);
    }
#pragma unroll
    for (int o = 32; o > 0; o >>= 1) s += __shfl_down(s, o, 64);
    __shared__ float sm[4];
    int lane = threadIdx.x & 63, wid = threadIdx.x >> 6;
    if (lane == 0) sm[wid] = s;
    __syncthreads();
    if (threadIdx.x == 0)
        partials[blockIdx.x] = sm[0] + sm[1] + sm[2] + sm[3];
}

__global__ void finalize_sum(const float* __restrict__ partials, int nparts,
                             float* __restrict__ out, int n)
{
    float s = 0.0f;
    for (int i = threadIdx.x; i < nparts; i += 256) s += partials[i];
#pragma unroll
    for (int o = 32; o > 0; o >>= 1) s += __shfl_down(s, o, 64);
    __shared__ float sm[4];
    int lane = threadIdx.x & 63, wid = threadIdx.x >> 6;
    if (lane == 0) sm[wid] = s;
    __syncthreads();
    if (threadIdx.x == 0)
        out[0] = (sm[0] + sm[1] + sm[2] + sm[3]) / (3.0f * (float)n);
}

// ---------------------------------------------------------------------------

extern "C" void kernel_launch(void* const* d_in, const int* in_sizes, int n_in,
                              void* d_out, int out_size, void* d_ws, size_t ws_size,
                              hipStream_t stream)
{
    const float* vs = (const float*)d_in[0];
    const float* vt = (const float*)d_in[1];
    int n = in_sizes[0] / 3;
    int F = in_sizes[2] / 3;

    int W = (int)(sqrt((double)n) + 0.5);
    int H = (W > 0) ? n / W : 0;
    bool grid_ok = (W > 1) && ((long long)W * H == n) &&
                   (2LL * (W - 1) * (H - 1) == F);

    float* partials = (float*)d_ws;

    if (grid_ok && (H % MK == 0)) {
        dim3 block(256, 1, 1);
        dim3 grid((W + 255) / 256, H / MK, 1);
        int nparts = grid.x * grid.y;
        hess_march2<<<grid, block, 0, stream>>>(vs, vt, partials, W, H);
        finalize_sum<<<1, 256, 0, stream>>>(partials, nparts, (float*)d_out, n);
    } else {
        int threads = 256;
        int blocks = (n + threads - 1) / threads;
        hess_gather<<<blocks, threads, 0, stream>>>(vs, vt, partials, W, H);
        finalize_sum<<<1, 256, 0, stream>>>(partials, blocks, (float*)d_out, n);
    }
}

// Round 9
// 28.822 us; speedup vs baseline: 4.6047x; 1.0703x over previous
//
#include <hip/hip_runtime.h>
#include <math.h>

// ---------------------------------------------------------------------------
// HessianLoss — march + face-payload sharing: every face computed ONCE.
// Thread owns column c (lane 0 of each wave is a GHOST: computes faces for
// the wave's left boundary, output masked; wave covers 63 output columns).
// Per steady-state row step:
//   - 2 own-column loads (rows r+2 of vs,vt); lane-63 patches right column
//   - build payloads F1=f1@(r,c), F2=f2@(r,c): {e02, e10, aw=area*g},
//     g role-independent -> contributions are just k (x) aw (18 FMA)
//   - F3 = shfl_up(F1), F5 = shfl_up(F6_old); F4,F6 carried registers
//   - 6 guarded contributions, square+weight, accumulate
// Face/role table (math identical to verified R6/R7/R8):
//   F1=f1@(r,c) i0      F2=f2@(r,c) i0      F3=f1@(r,c-1) i1
//   F4=f1@(r-1,c-1) i2  F5=f2@(r-1,c-1) i1  F6=f2@(r-1,c) i2
// Degenerate/clamped faces produce NaN payloads but every such contribution
// is guarded off (rp/rm/cp/cm); invalid lanes overwrite s=0 before reduce.
// No __threadfence (R3-R5: L2 invalidate, +80us). No LDS staging (R3).
// Reduction: per-block partial stores + tiny reduce kernel (R8).
// ---------------------------------------------------------------------------

struct FP { float ex, ey, ez, hx, hy, hz, w[9]; };  // e02, e10, aw=area*g

__device__ __forceinline__ float3 d3(float3 t, float3 v)
{
    return make_float3(t.x - v.x, t.y - v.y, t.z - v.z);
}
__device__ __forceinline__ float3 shfl_dn3(float3 v)
{
    return make_float3(__shfl_down(v.x, 1, 64), __shfl_down(v.y, 1, 64),
                       __shfl_down(v.z, 1, 64));
}

__device__ __forceinline__ FP mkface(float3 V0, float3 V1, float3 V2,
                                     float3 D0, float3 D1, float3 D2)
{
    float ax = V2.x - V1.x, ay = V2.y - V1.y, az = V2.z - V1.z;   // v21
    float bx = V0.x - V2.x, by = V0.y - V2.y, bz = V0.z - V2.z;   // v02
    float cx = V1.x - V0.x, cy = V1.y - V0.y, cz = V1.z - V0.z;   // v10
    float nx = ay * bz - az * by;
    float ny = az * bx - ax * bz;
    float nz = ax * by - ay * bx;
    float A2 = nx * nx + ny * ny + nz * nz;
    float invA2 = __builtin_amdgcn_rcpf(A2);
    float sc = 0.5f * __builtin_amdgcn_rsqf(A2);      // area / A2
    float e1x = ny * bz - nz * by, e1y = nz * bx - nx * bz, e1z = nx * by - ny * bx;
    float e2x = ny * cz - nz * cy, e2y = nz * cx - nx * cz, e2z = nx * cy - ny * cx;
    FP f;
    f.ex = e1x * invA2; f.ey = e1y * invA2; f.ez = e1z * invA2;   // e02
    f.hx = e2x * invA2; f.hy = e2y * invA2; f.hz = e2z * invA2;   // e10
    float s1x = e1x * sc, s1y = e1y * sc, s1z = e1z * sc;         // area*e02
    float s2x = e2x * sc, s2y = e2y * sc, s2z = e2z * sc;         // area*e10
    float d1x = D1.x - D0.x, d1y = D1.y - D0.y, d1z = D1.z - D0.z;
    float d2x = D2.x - D0.x, d2y = D2.y - D0.y, d2z = D2.z - D0.z;
    f.w[0] = s1x * d1x + s2x * d2x;
    f.w[1] = s1x * d1y + s2x * d2y;
    f.w[2] = s1x * d1z + s2x * d2z;
    f.w[3] = s1y * d1x + s2y * d2x;
    f.w[4] = s1y * d1y + s2y * d2y;
    f.w[5] = s1y * d1z + s2y * d2z;
    f.w[6] = s1z * d1x + s2z * d2x;
    f.w[7] = s1z * d1y + s2z * d2y;
    f.w[8] = s1z * d1z + s2z * d2z;
    return f;
}

__device__ __forceinline__ FP shfl_up_fp(const FP& f)
{
    FP r;
    r.ex = __shfl_up(f.ex, 1, 64); r.ey = __shfl_up(f.ey, 1, 64);
    r.ez = __shfl_up(f.ez, 1, 64);
    r.hx = __shfl_up(f.hx, 1, 64); r.hy = __shfl_up(f.hy, 1, 64);
    r.hz = __shfl_up(f.hz, 1, 64);
#pragma unroll
    for (int i = 0; i < 9; ++i) r.w[i] = __shfl_up(f.w[i], 1, 64);
    return r;
}

// ROLE: 0 -> i0 (k=-(e02+e10)), 1 -> i1 (k=e02), 2 -> i2 (k=e10)
template <int ROLE>
__device__ __forceinline__ void addc(const FP& f, float acc[6][3])
{
    float K[3];
    if (ROLE == 1)      { K[0] = f.ex; K[1] = f.ey; K[2] = f.ez; }
    else if (ROLE == 2) { K[0] = f.hx; K[1] = f.hy; K[2] = f.hz; }
    else { K[0] = -(f.ex + f.hx); K[1] = -(f.ey + f.hy); K[2] = -(f.ez + f.hz); }
    const int pa[6] = {0, 1, 2, 0, 0, 1};
    const int pb[6] = {0, 1, 2, 1, 2, 2};
#pragma unroll
    for (int p = 0; p < 6; ++p)
#pragma unroll
        for (int cc = 0; cc < 3; ++cc)
            acc[p][cc] += K[pa[p]] * f.w[pb[p] * 3 + cc];
}

__device__ __forceinline__ float sq_acc(const float acc[6][3])
{
    float s1 = 0.0f, s2 = 0.0f;
#pragma unroll
    for (int p = 0; p < 3; ++p)
#pragma unroll
        for (int cc = 0; cc < 3; ++cc) s1 += acc[p][cc] * acc[p][cc];
#pragma unroll
    for (int p = 3; p < 6; ++p)
#pragma unroll
        for (int cc = 0; cc < 3; ++cc) s2 += acc[p][cc] * acc[p][cc];
    return s1 + 2.0f * s2;
}

#define MK 4       // rows marched per thread
#define OUTW 63    // output columns per wave (lane 0 = ghost)
#define BOUT (4 * OUTW)  // 252 output columns per 256-thread block

__global__ __launch_bounds__(256)
void hess_face(const float* __restrict__ vsf, const float* __restrict__ vtf,
               float* __restrict__ partials, int W, int H)
{
    const float3* vs = (const float3*)vsf;
    const float3* vt = (const float3*)vtf;
    const int tid = threadIdx.x, lane = tid & 63, wvid = tid >> 6;
    const int c = blockIdx.x * BOUT + wvid * OUTW + lane - 1;
    const int r0 = blockIdx.y * MK;
    const bool valid = (lane > 0) && (c < W);   // lane>0 => c >= 0
    const bool cp = (c < W - 1), cm = (c > 0);
    const int cL = (c < 0) ? 0 : ((c > W - 1) ? W - 1 : c);
    const int cR = (c + 1 > W - 1) ? W - 1 : ((c + 1 < 0) ? 0 : c + 1);

    // ---- prologue: rows r0-1 (clamped) and r0; build initial F4, F6 ----
    const int otop = (r0 > 0 ? r0 - 1 : 0) * W;
    const int obot = r0 * W;
    float3 V00 = vs[otop + cL];  float3 D00 = d3(vt[otop + cL], V00);
    float3 V10 = vs[obot + cL];  float3 D10 = d3(vt[obot + cL], V10);
    float3 V01 = shfl_dn3(V00),  D01 = shfl_dn3(D00);
    float3 V11 = shfl_dn3(V10),  D11 = shfl_dn3(D10);
    if (lane == 63) {
        float3 v = vs[otop + cR]; V01 = v; D01 = d3(vt[otop + cR], v);
        v = vs[obot + cR];        V11 = v; D11 = d3(vt[obot + cR], v);
    }
    FP F1p = mkface(V00, V01, V11, D00, D01, D11);   // f1@(r0-1,c)
    FP F2p = mkface(V00, V11, V10, D00, D11, D10);   // f2@(r0-1,c)
    FP F4 = shfl_up_fp(F1p);                         // -> f1@(r0-1,c-1)
    FP F6 = F2p;                                     // -> f2@(r0-1,c)
    // advance to rows r0, r0+1
    V00 = V10; D00 = D10; V01 = V11; D01 = D11;
    const int o1 = (r0 + 1 < H ? r0 + 1 : H - 1) * W;
    V10 = vs[o1 + cL]; D10 = d3(vt[o1 + cL], V10);
    V11 = shfl_dn3(V10); D11 = shfl_dn3(D10);
    if (lane == 63) {
        float3 v = vs[o1 + cR]; V11 = v; D11 = d3(vt[o1 + cR], v);
    }

    float s = 0.0f;
#pragma unroll
    for (int k = 0; k < MK; ++k) {
        const int r = r0 + k;
        const bool rp = (r < H - 1), rm = (r > 0);   // wave-uniform

        // prefetch row r+2 (own column; lane-63 also right column)
        const int ob = (r + 2 < H ? r + 2 : H - 1) * W;
        float3 P = vs[ob + cL];
        float3 TP = vt[ob + cL];
        float3 PR = P, TPR = TP;
        if (lane == 63) { PR = vs[ob + cR]; TPR = vt[ob + cR]; }

        // build this row's faces (once per face, owner lane)
        FP F1 = mkface(V00, V01, V11, D00, D01, D11);  // f1@(r,c)
        FP F2 = mkface(V00, V11, V10, D00, D11, D10);  // f2@(r,c)
        FP F3 = shfl_up_fp(F1);                        // f1@(r,c-1)
        FP F5 = shfl_up_fp(F6);                        // f2@(r-1,c-1)

        float acc[6][3] = {};
        if (rp && cp) { addc<0>(F1, acc); addc<0>(F2, acc); }
        if (rp && cm) addc<1>(F3, acc);
        if (rm && cm) { addc<2>(F4, acc); addc<1>(F5, acc); }
        if (rm && cp) addc<2>(F6, acc);
        s += sq_acc(acc);

        // rotate
        V00 = V10; D00 = D10; V01 = V11; D01 = D11;
        V10 = P;   D10 = d3(TP, P);
        V11 = shfl_dn3(V10); D11 = shfl_dn3(D10);
        if (lane == 63) { V11 = PR; D11 = d3(TPR, PR); }
        F4 = F3; F6 = F2;
    }

    if (!valid) s = 0.0f;   // overwrite: kills ghost/out-of-range NaN

    // ---- block reduce + plain partial store ----
#pragma unroll
    for (int o = 32; o > 0; o >>= 1) s += __shfl_down(s, o, 64);
    __shared__ float sm[4];
    if (lane == 0) sm[wvid] = s;
    __syncthreads();
    if (tid == 0)
        partials[blockIdx.y * gridDim.x + blockIdx.x] = sm[0] + sm[1] + sm[2] + sm[3];
}

// ------------- fallback: 1-D per-vertex gather (any grid dims) -------------

__global__ void hess_gather(const float* __restrict__ vsf, const float* __restrict__ vtf,
                            float* __restrict__ partials, int W, int H)
{
    const float3* vs = (const float3*)vsf;
    const float3* vt = (const float3*)vtf;
    int v = blockIdx.x * blockDim.x + threadIdx.x;
    int n = W * H;
    float s = 0.0f;
    if (v < n) {
        int r = v / W;
        int c = v - r * W;
        bool rp = (r < H - 1), rm = (r >= 1), cp = (c < W - 1), cm = (c >= 1);
        int i01 = cp ? v + 1 : v;
        int i11 = (rp && cp) ? v + W + 1 : v;
        int i10 = rp ? v + W : v;
        int im  = cm ? v - 1 : v;
        int idd = (rm && cm) ? v - W - 1 : v;
        int iu  = rm ? v - W : v;
        float3 P00 = vs[v],  D00 = d3(vt[v], P00);
        float3 P01 = vs[i01], D01 = d3(vt[i01], P01);
        float3 P11 = vs[i11], D11 = d3(vt[i11], P11);
        float3 P10 = vs[i10], D10 = d3(vt[i10], P10);
        float3 Pm  = vs[im],  Dm  = d3(vt[im], Pm);
        float3 Pdd = vs[idd], Ddd = d3(vt[idd], Pdd);
        float3 Pu  = vs[iu],  Du  = d3(vt[iu], Pu);
        float acc[6][3] = {};
        if (rp && cp) {
            addc<0>(mkface(P00, P01, P11, D00, D01, D11), acc);
            addc<0>(mkface(P00, P11, P10, D00, D11, D10), acc);
        }
        if (rp && cm)
            addc<1>(mkface(Pm, P00, P10, Dm, D00, D10), acc);
        if (rm && cm) {
            addc<2>(mkface(Pdd, Pu, P00, Ddd, Du, D00), acc);
            addc<1>(mkface(Pdd, P00, Pm, Ddd, D00, Dm), acc);
        }
        if (rm && cp)
            addc<2>(mkface(Pu, P01, P00, Du, D01, D00), acc);
        s = sq_acc(acc);
    }
#pragma unroll
    for (int o = 32; o > 0; o >>= 1) s += __shfl_down(s, o, 64);
    __shared__ float sm[4];
    int lane = threadIdx.x & 63, wid = threadIdx.x >> 6;
    if (lane == 0) sm[wid] = s;
    __syncthreads();
    if (threadIdx.x == 0)
        partials[blockIdx.x] = sm[0] + sm[1] + sm[2] + sm[3];
}

__global__ void finalize_sum(const float* __restrict__ partials, int nparts,
                             float* __restrict__ out, int n)
{
    float s = 0.0f;
    for (int i = threadIdx.x; i < nparts; i += 256) s += partials[i];
#pragma unroll
    for (int o = 32; o > 0; o >>= 1) s += __shfl_down(s, o, 64);
    __shared__ float sm[4];
    int lane = threadIdx.x & 63, wid = threadIdx.x >> 6;
    if (lane == 0) sm[wid] = s;
    __syncthreads();
    if (threadIdx.x == 0)
        out[0] = (sm[0] + sm[1] + sm[2] + sm[3]) / (3.0f * (float)n);
}

// ---------------------------------------------------------------------------

extern "C" void kernel_launch(void* const* d_in, const int* in_sizes, int n_in,
                              void* d_out, int out_size, void* d_ws, size_t ws_size,
                              hipStream_t stream)
{
    const float* vs = (const float*)d_in[0];
    const float* vt = (const float*)d_in[1];
    int n = in_sizes[0] / 3;
    int F = in_sizes[2] / 3;

    int W = (int)(sqrt((double)n) + 0.5);
    int H = (W > 0) ? n / W : 0;
    bool grid_ok = (W > 1) && ((long long)W * H == n) &&
                   (2LL * (W - 1) * (H - 1) == F);

    float* partials = (float*)d_ws;

    if (grid_ok && (H % MK == 0)) {
        dim3 block(256, 1, 1);
        dim3 grid((W + BOUT - 1) / BOUT, H / MK, 1);
        int nparts = grid.x * grid.y;
        hess_face<<<grid, block, 0, stream>>>(vs, vt, partials, W, H);
        finalize_sum<<<1, 256, 0, stream>>>(partials, nparts, (float*)d_out, n);
    } else {
        int threads = 256;
        int blocks = (n + threads - 1) / threads;
        hess_gather<<<blocks, threads, 0, stream>>>(vs, vt, partials, W, H);
        finalize_sum<<<1, 256, 0, stream>>>(partials, blocks, (float*)d_out, n);
    }
}